// Round 4
// 280.606 us; speedup vs baseline: 1.0637x; 1.0637x over previous
//
#include <hip/hip_runtime.h>
#include <math.h>

#define NROWS 8192
#define DDIM  2048
#define NEXP  4096
#define TK    8
#define KSPLIT 4
#define KRANGE (DDIM / KSPLIT)   // 512
#define RB     32                // rows per block (kernel 1)

typedef float  f4 __attribute__((ext_vector_type(4)));
typedef double d2 __attribute__((ext_vector_type(2)));

// ---------------- Kernel 1: fp64 partial GEMM, K-split 4 (round-0 proven) ----
// grid 1024 = 256 row-blocks x 4 K-parts; block 256 thr; 32x128 tile, 4x4/thread.
// Partial P[kp] (fp64, 1KB) stored in the front 4KB of each row's score slot.
__global__ __launch_bounds__(256, 4) void pkr_gemm64(const float* __restrict__ x,
                                                     const float* __restrict__ w1,
                                                     const float* __restrict__ w2,
                                                     float* __restrict__ out) {
  __shared__ double xsd[32][34];   // [k][row], stride 34 -> 16B-aligned d2 reads
  __shared__ float  wsf[32][132];  // [k][col], stride 132 -> 16B-aligned f4 reads

  const int tid   = threadIdx.x;
  const int rb    = blockIdx.x >> 2;
  const int kp    = blockIdx.x & 3;
  const int rows0 = rb * RB;
  const int kbase = kp * KRANGE;

  const int rh = tid >> 5;   // 0..7  -> rows rh*4..+3
  const int ch = tid & 31;   // 0..31 -> cols ch*4..+3

  const int sxr = tid >> 3;          // 0..31
  const int sxk = (tid & 7) * 4;     // 0..28
  const float* xrow = x + (size_t)(rows0 + sxr) * DDIM + kbase + sxk;

  double acc[4][4] = {};

  for (int cch = 0; cch < KRANGE / 32; ++cch) {   // 16 chunks of K=32
    const int k0 = cch * 32;
    // stage x tile (32 rows x 32 k), transposed, converted to double once
    f4 xv = *(const f4*)(xrow + k0);
#pragma unroll
    for (int q = 0; q < 4; ++q) xsd[sxk + q][sxr] = (double)xv[q];
    // stage W tile (128 cols x 32 k), raw float
#pragma unroll
    for (int i = 0; i < 4; ++i) {
      const int idx = i * 256 + tid;
      const int c2  = idx >> 3;          // 0..127
      const int kk  = (idx & 7) * 4;     // 0..28
      const float* wr = (c2 < 64) ? (w1 + (size_t)c2 * DDIM)
                                  : (w2 + (size_t)(c2 - 64) * DDIM);
      f4 wv = *(const f4*)(wr + kbase + k0 + kk);
#pragma unroll
      for (int q = 0; q < 4; ++q) wsf[kk + q][c2] = wv[q];
    }
    __syncthreads();

#pragma unroll
    for (int k = 0; k < 32; ++k) {
      const d2 x01 = *(const d2*)&xsd[k][rh * 4];
      const d2 x23 = *(const d2*)&xsd[k][rh * 4 + 2];
      const f4 wq  = *(const f4*)&wsf[k][ch * 4];
      const double xd[4] = { x01[0], x01[1], x23[0], x23[1] };
      double wd[4];
#pragma unroll
      for (int b = 0; b < 4; ++b) wd[b] = (double)wq[b];
#pragma unroll
      for (int a = 0; a < 4; ++a)
#pragma unroll
        for (int b = 0; b < 4; ++b)
          acc[a][b] += xd[a] * wd[b];
    }
    __syncthreads();
  }

  double* P = (double*)(out + (size_t)2 * NROWS * TK);
#pragma unroll
  for (int a = 0; a < 4; ++a) {
    double* dst = P + (size_t)(rows0 + rh * 4 + a) * (NEXP / 2) + kp * 128 + ch * 4;
    d2 lo; lo[0] = acc[a][0]; lo[1] = acc[a][1];
    d2 hi; hi[0] = acc[a][2]; hi[1] = acc[a][3];
    *(d2*)dst       = lo;
    *(d2*)(dst + 2) = hi;
  }
}

// ---- bitonic sort of 64 lanes, best-first; order: (val desc, idx asc) ----
__device__ __forceinline__ void bitonic64(double& v, int& idx, int lane) {
#pragma unroll
  for (int k = 2; k <= 64; k <<= 1) {
#pragma unroll
    for (int j = k >> 1; j > 0; j >>= 1) {
      const double ov = __shfl_xor(v, j);
      const int    oi = __shfl_xor(idx, j);
      const bool obetter = (ov > v) || (ov == v && oi < idx);
      const bool lower   = (lane & j) == 0;
      const bool up      = (lane & k) == 0;   // best-first segment
      if ((lower == up) ? obetter : !obetter) { v = ov; idx = oi; }
    }
  }
}

// ---------------- Kernel 2: combine partials + expand + top8 + softmax ----------
// 4 rows per block (one wave each), 2048 blocks x 256 thr.
__global__ __launch_bounds__(256) void pkr_finish(float* __restrict__ out) {
  const int lane = threadIdx.x & 63;
  const int wv   = threadIdx.x >> 6;
  const int row  = blockIdx.x * 4 + wv;

  const double* Pr = (const double*)(out + (size_t)2 * NROWS * TK) + (size_t)row * (NEXP / 2);
  double s1 = 0.0, s2 = 0.0;
#pragma unroll
  for (int p = 0; p < KSPLIT; ++p) {
    s1 += Pr[p * 128 + lane];
    s2 += Pr[p * 128 + 64 + lane];
  }

  __shared__ double sh1[4][64], sh2[4][64];
  sh1[wv][lane] = s1;
  sh2[wv][lane] = s2;
  __syncthreads();   // memory fence: all partial reads precede slot overwrite

  // ---- scores[row][i*64+j] = float(s1[i] + s2[j]), 1KB contiguous per instr ----
  {
    float* srow = out + (size_t)2 * NROWS * TK + (size_t)row * NEXP;
    const int il = lane >> 4;          // 0..3
    const int jq = (lane & 15) * 4;    // 0..60
    const double sj0 = sh2[wv][jq + 0], sj1 = sh2[wv][jq + 1];
    const double sj2 = sh2[wv][jq + 2], sj3 = sh2[wv][jq + 3];
#pragma unroll
    for (int i0 = 0; i0 < 64; i0 += 4) {
      const double si = sh1[wv][i0 + il];
      f4 v;
      v[0] = (float)(si + sj0);
      v[1] = (float)(si + sj1);
      v[2] = (float)(si + sj2);
      v[3] = (float)(si + sj3);
      *(f4*)(srow + (size_t)(i0 + il) * 64 + jq) = v;
    }
  }

  // ---- top8 of s1 and s2 via full bitonic sort (tie-break: idx asc) ----
  double v1 = s1; int i1 = lane;
  bitonic64(v1, i1, lane);
  double v2 = s2; int i2 = lane;
  bitonic64(v2, i2, lane);

  // ---- 64 candidate sums (top8 x top8), top8 by (val desc, flat idx asc) ----
  const double ca = __shfl(v1, lane >> 3);
  const int    ia = __shfl(i1, lane >> 3);
  const double cb = __shfl(v2, lane & 7);
  const int    ib = __shfl(i2, lane & 7);
  double cv = ca + cb;
  int    ci = ia * 64 + ib;
  bitonic64(cv, ci, lane);

  // ---- softmax over lanes 0..7 + emit ----
  const double vmax = __shfl(cv, 0);
  float e = expf((float)(cv - vmax));
  float sum = e;
#pragma unroll
  for (int off = 1; off < 8; off <<= 1) sum += __shfl_xor(sum, off);  // 8-group sum
  if (lane < 8) {
    out[(size_t)row * TK + lane]                      = (float)ci;
    out[(size_t)NROWS * TK + (size_t)row * TK + lane] = e / sum;
  }
}

extern "C" void kernel_launch(void* const* d_in, const int* in_sizes, int n_in,
                              void* d_out, int out_size, void* d_ws, size_t ws_size,
                              hipStream_t stream) {
  const float* x  = (const float*)d_in[0];
  const float* w1 = (const float*)d_in[1];
  const float* w2 = (const float*)d_in[2];
  float* out = (float*)d_out;

  hipLaunchKernelGGL(pkr_gemm64, dim3((NROWS / RB) * KSPLIT), dim3(256), 0, stream,
                     x, w1, w2, out);
  hipLaunchKernelGGL(pkr_finish, dim3(NROWS / 4), dim3(256), 0, stream, out);
}

// Round 5
// 273.869 us; speedup vs baseline: 1.0899x; 1.0246x over previous
//
#include <hip/hip_runtime.h>
#include <math.h>

#define NROWS 8192
#define DDIM  2048
#define NEXP  4096
#define TK    8
#define KSPLIT 4
#define KRANGE (DDIM / KSPLIT)   // 512
#define BM     64                // rows per block (kernel 1)

typedef float  f4 __attribute__((ext_vector_type(4)));
typedef double d2 __attribute__((ext_vector_type(2)));

// ---------------- Kernel 1: fp64 partial GEMM, K-split 4, 4x8/thread ----------
// grid 512 = 128 row-blocks x 4 K-parts; block 256 thr; 64x128 tile.
// Both operands staged to LDS as fp64 (cvt once at staging; inner loop = pure dFMA).
// Thread (rh,ch): rows rh*4..+3, cols {g*32 + 2*ch, +1} for g=0..3 -> all frag
// reads are d2 at 16B-lane-stride => <=2-way bank alias (free).
// Partial P[kp] (fp64, 1KB) layout identical to round-0 (finish reader unchanged).
__global__ __launch_bounds__(256, 2) void pkr_gemm64w(const float* __restrict__ x,
                                                      const float* __restrict__ w1,
                                                      const float* __restrict__ w2,
                                                      float* __restrict__ out) {
  __shared__ double xsd[32][66];    // [k][row]  16.9 KB; row 528B (16B-aligned)
  __shared__ double wsd[32][130];   // [k][col]  33.3 KB; row 1040B (16B-aligned)

  const int tid   = threadIdx.x;
  const int rb    = blockIdx.x >> 2;
  const int kp    = blockIdx.x & 3;
  const int rows0 = rb * BM;
  const int kbase = kp * KRANGE;

  const int rh = tid >> 4;    // 0..15 -> rows rh*4..+3
  const int ch = tid & 15;    // cols g*32 + ch*2 + {0,1}

  // staging maps (coalesced f4 loads)
  const int sxr = tid >> 3;          // 0..31
  const int sxk = (tid & 7) * 4;     // 0..28
  const float* xr0 = x + (size_t)(rows0 + sxr) * DDIM + kbase + sxk;
  const float* xr1 = xr0 + (size_t)32 * DDIM;

  const int swc = tid >> 1;          // 0..127
  const int swk = (tid & 1) * 16;    // 0,16
  const float* wr = ((swc < 64) ? (w1 + (size_t)swc * DDIM)
                                : (w2 + (size_t)(swc - 64) * DDIM)) + kbase + swk;

  double acc[4][8] = {};

  for (int cch = 0; cch < KRANGE / 32; ++cch) {   // 16 chunks of K=32
    const int k0 = cch * 32;
    // ---- stage x tile (64 rows x 32 k) -> fp64 [k][row] ----
    {
      f4 a = *(const f4*)(xr0 + k0);
      f4 b = *(const f4*)(xr1 + k0);
#pragma unroll
      for (int q = 0; q < 4; ++q) {
        xsd[sxk + q][sxr]      = (double)a[q];
        xsd[sxk + q][32 + sxr] = (double)b[q];
      }
    }
    // ---- stage W tile (128 cols x 32 k) -> fp64 [k][col] (cvt once here) ----
#pragma unroll
    for (int p = 0; p < 4; ++p) {
      f4 wv = *(const f4*)(wr + k0 + p * 4);
#pragma unroll
      for (int q = 0; q < 4; ++q)
        wsd[swk + p * 4 + q][swc] = (double)wv[q];
    }
    __syncthreads();

#pragma unroll
    for (int k = 0; k < 32; ++k) {
      const d2 x01 = *(const d2*)&xsd[k][rh * 4];       // broadcast within wave
      const d2 x23 = *(const d2*)&xsd[k][rh * 4 + 2];
      const double xd[4] = { x01[0], x01[1], x23[0], x23[1] };
      d2 wg[4];
#pragma unroll
      for (int g = 0; g < 4; ++g) wg[g] = *(const d2*)&wsd[k][g * 32 + ch * 2];
#pragma unroll
      for (int a = 0; a < 4; ++a)
#pragma unroll
        for (int g = 0; g < 4; ++g) {
          acc[a][2 * g]     += xd[a] * wg[g][0];
          acc[a][2 * g + 1] += xd[a] * wg[g][1];
        }
    }
    __syncthreads();
  }

  // P[row][kp*128 + g*32 + ch*2 + {0,1}] ; cols 0..63 = s1 (W1), 64..127 = s2 (W2)
  double* P = (double*)(out + (size_t)2 * NROWS * TK);
#pragma unroll
  for (int a = 0; a < 4; ++a) {
    double* dst = P + (size_t)(rows0 + rh * 4 + a) * (NEXP / 2) + kp * 128;
#pragma unroll
    for (int g = 0; g < 4; ++g) {
      d2 v; v[0] = acc[a][2 * g]; v[1] = acc[a][2 * g + 1];
      *(d2*)(dst + g * 32 + ch * 2) = v;
    }
  }
}

// ---- bitonic sort of 64 lanes, best-first; order: (val desc, idx asc) ----
__device__ __forceinline__ void bitonic64(double& v, int& idx, int lane) {
#pragma unroll
  for (int k = 2; k <= 64; k <<= 1) {
#pragma unroll
    for (int j = k >> 1; j > 0; j >>= 1) {
      const double ov = __shfl_xor(v, j);
      const int    oi = __shfl_xor(idx, j);
      const bool obetter = (ov > v) || (ov == v && oi < idx);
      const bool lower   = (lane & j) == 0;
      const bool up      = (lane & k) == 0;   // best-first segment
      if ((lower == up) ? obetter : !obetter) { v = ov; idx = oi; }
    }
  }
}

// ---------------- Kernel 2: combine partials + expand + top8 + softmax ----------
// 4 rows per block (one wave each), 2048 blocks x 256 thr.  (round-4 proven)
__global__ __launch_bounds__(256) void pkr_finish(float* __restrict__ out) {
  const int lane = threadIdx.x & 63;
  const int wv   = threadIdx.x >> 6;
  const int row  = blockIdx.x * 4 + wv;

  const double* Pr = (const double*)(out + (size_t)2 * NROWS * TK) + (size_t)row * (NEXP / 2);
  double s1 = 0.0, s2 = 0.0;
#pragma unroll
  for (int p = 0; p < KSPLIT; ++p) {
    s1 += Pr[p * 128 + lane];
    s2 += Pr[p * 128 + 64 + lane];
  }

  __shared__ double sh1[4][64], sh2[4][64];
  sh1[wv][lane] = s1;
  sh2[wv][lane] = s2;
  __syncthreads();   // memory fence: all partial reads precede slot overwrite

  // ---- scores[row][i*64+j] = float(s1[i] + s2[j]), 1KB contiguous per instr ----
  {
    float* srow = out + (size_t)2 * NROWS * TK + (size_t)row * NEXP;
    const int il = lane >> 4;          // 0..3
    const int jq = (lane & 15) * 4;    // 0..60
    const double sj0 = sh2[wv][jq + 0], sj1 = sh2[wv][jq + 1];
    const double sj2 = sh2[wv][jq + 2], sj3 = sh2[wv][jq + 3];
#pragma unroll
    for (int i0 = 0; i0 < 64; i0 += 4) {
      const double si = sh1[wv][i0 + il];
      f4 v;
      v[0] = (float)(si + sj0);
      v[1] = (float)(si + sj1);
      v[2] = (float)(si + sj2);
      v[3] = (float)(si + sj3);
      *(f4*)(srow + (size_t)(i0 + il) * 64 + jq) = v;
    }
  }

  // ---- top8 of s1 and s2 via full bitonic sort (tie-break: idx asc) ----
  double v1 = s1; int i1 = lane;
  bitonic64(v1, i1, lane);
  double v2 = s2; int i2 = lane;
  bitonic64(v2, i2, lane);

  // ---- 64 candidate sums (top8 x top8), top8 by (val desc, flat idx asc) ----
  const double ca = __shfl(v1, lane >> 3);
  const int    ia = __shfl(i1, lane >> 3);
  const double cb = __shfl(v2, lane & 7);
  const int    ib = __shfl(i2, lane & 7);
  double cv = ca + cb;
  int    ci = ia * 64 + ib;
  bitonic64(cv, ci, lane);

  // ---- softmax over lanes 0..7 + emit ----
  const double vmax = __shfl(cv, 0);
  float e = expf((float)(cv - vmax));
  float sum = e;
#pragma unroll
  for (int off = 1; off < 8; off <<= 1) sum += __shfl_xor(sum, off);  // 8-group sum
  if (lane < 8) {
    out[(size_t)row * TK + lane]                      = (float)ci;
    out[(size_t)NROWS * TK + (size_t)row * TK + lane] = e / sum;
  }
}

extern "C" void kernel_launch(void* const* d_in, const int* in_sizes, int n_in,
                              void* d_out, int out_size, void* d_ws, size_t ws_size,
                              hipStream_t stream) {
  const float* x  = (const float*)d_in[0];
  const float* w1 = (const float*)d_in[1];
  const float* w2 = (const float*)d_in[2];
  float* out = (float*)d_out;

  hipLaunchKernelGGL(pkr_gemm64w, dim3((NROWS / BM) * KSPLIT), dim3(256), 0, stream,
                     x, w1, w2, out);
  hipLaunchKernelGGL(pkr_finish, dim3(NROWS / 4), dim3(256), 0, stream, out);
}